// Round 6
// baseline (304.947 us; speedup 1.0000x reference)
//
#include <hip/hip_runtime.h>
#include <math.h>
#include <stdint.h>

typedef __bf16 bf16;
typedef bf16 bf16x8 __attribute__((ext_vector_type(8)));
typedef float floatx4 __attribute__((ext_vector_type(4)));

static constexpr int Sq = 2048, Dm = 1024, Hh = 16, HDim = 64;

#define GAS __attribute__((address_space(1)))
#define LAS __attribute__((address_space(3)))

// async global->LDS DMA, 16 B per lane; lds base wave-uniform, lane i -> base + i*16
__device__ __forceinline__ void dma16(const void* g, void* l) {
    __builtin_amdgcn_global_load_lds((const GAS void*)g, (LAS void*)l, 16, 0, 0);
}

__device__ __forceinline__ uint32_t pk_bf16(float a, float b) {
    unsigned short lo = __builtin_bit_cast(unsigned short, (bf16)a);
    unsigned short hi = __builtin_bit_cast(unsigned short, (bf16)b);
    return (uint32_t)lo | ((uint32_t)hi << 16);
}

// ---------------------------------------------------------------------------
// Kernel A: x fp32 -> bf16 (one pass).  8 elems/thread.
// ---------------------------------------------------------------------------
__global__ __launch_bounds__(256)
void conv_x(const float* __restrict__ x, bf16* __restrict__ xb)
{
    const size_t i = ((size_t)blockIdx.x * 256 + threadIdx.x) * 8;
    float4 f0 = *(const float4*)(x + i);
    float4 f1 = *(const float4*)(x + i + 4);
    bf16x8 v;
    v[0]=(bf16)f0.x; v[1]=(bf16)f0.y; v[2]=(bf16)f0.z; v[3]=(bf16)f0.w;
    v[4]=(bf16)f1.x; v[5]=(bf16)f1.y; v[6]=(bf16)f1.z; v[7]=(bf16)f1.w;
    *(bf16x8*)(xb + i) = v;
}

// ---------------------------------------------------------------------------
// Kernel 0: weight prep.  W fp32 [k][n] -> Wt bf16 [n][k], 4 matrices.
// ---------------------------------------------------------------------------
__global__ __launch_bounds__(256)
void prep_weights(const float* __restrict__ Wq, const float* __restrict__ Wk,
                  const float* __restrict__ Wv, const float* __restrict__ Wo,
                  bf16* __restrict__ Wt)
{
    const int w = blockIdx.z;
    const float* W = (w == 0) ? Wq : (w == 1) ? Wk : (w == 2) ? Wv : Wo;
    bf16* dst = Wt + (size_t)w * 1024 * 1024;
    const int k0 = blockIdx.x * 64, n0 = blockIdx.y * 64;
    __shared__ uint32_t Tl[64][33];
    const int t = threadIdx.x;
    {
        const int c8 = (t & 7) * 8;
        const int kp = t >> 3;
        const float* r0 = W + (size_t)(k0 + 2 * kp) * 1024 + n0 + c8;
        const float* r1 = r0 + 1024;
        float4 a0 = *(const float4*)r0, a1 = *(const float4*)(r0 + 4);
        float4 b0 = *(const float4*)r1, b1 = *(const float4*)(r1 + 4);
        float ra[8] = {a0.x, a0.y, a0.z, a0.w, a1.x, a1.y, a1.z, a1.w};
        float rb[8] = {b0.x, b0.y, b0.z, b0.w, b1.x, b1.y, b1.z, b1.w};
#pragma unroll
        for (int j = 0; j < 8; j++)
            Tl[c8 + j][kp] = pk_bf16(ra[j], rb[j]);
    }
    __syncthreads();
    {
        const int c = t >> 2, dq = (t & 3) * 8;
        uint32_t d[8];
#pragma unroll
        for (int i = 0; i < 8; i++) d[i] = Tl[c][dq + i];
        uint32_t* o = (uint32_t*)(dst + (size_t)(n0 + c) * 1024 + k0 + dq * 2);
        *(uint4*)o       = make_uint4(d[0], d[1], d[2], d[3]);
        *(uint4*)(o + 4) = make_uint4(d[4], d[5], d[6], d[7]);
    }
}

// ---------------------------------------------------------------------------
// Kernel 1: QKV projection.  AMODE=1: bf16 xb via DMA (primary);
// AMODE=0: fp32 x (fallback).  128x128 tile, BK=64.
// K output pre-scaled by 0.125*log2(e) (softmax runs in exp2 domain).
// ---------------------------------------------------------------------------
template <int AMODE>
__global__ __launch_bounds__(256, 2)
void qkv_gemm(const float* __restrict__ x, const bf16* __restrict__ xb,
              const bf16* __restrict__ Wt,
              bf16* __restrict__ Qb, bf16* __restrict__ Kb, bf16* __restrict__ VT)
{
    const int zz = blockIdx.z;
    const bf16* Wsel = Wt + (size_t)zz * 1024 * 1024;

    __shared__ __align__(16) unsigned char smem[34816];
    bf16 (*As1)[64] = (bf16(*)[64])smem;
    bf16 (*As0)[72] = (bf16(*)[72])smem;
    bf16 (*Bs)[64]  = (bf16(*)[64])(smem + (AMODE ? 16384 : 18432));

    const int tid  = threadIdx.x;
    const int wave = tid >> 6, lane = tid & 63, quad = lane >> 4, l16 = lane & 15;
    const int bm = blockIdx.y * 128, bn = blockIdx.x * 128;
    const int wm = (wave >> 1) * 64, wn = (wave & 1) * 64;

    floatx4 acc[4][4];
#pragma unroll
    for (int i = 0; i < 4; i++)
#pragma unroll
        for (int j = 0; j < 4; j++) acc[i][j] = (floatx4){0.f, 0.f, 0.f, 0.f};

    for (int k0 = 0; k0 < 1024; k0 += 64) {
        __syncthreads();
#pragma unroll
        for (int i = 0; i < 4; i++) {
            const int row = wave * 32 + i * 8 + (lane >> 3);
            const int lb  = (lane & 7) ^ (row & 7);
            const bf16* g = Wsel + (size_t)(bn + row) * 1024 + k0 + lb * 8;
            dma16((const void*)g, (void*)&Bs[wave * 32 + i * 8][0]);
        }
        if (AMODE) {
#pragma unroll
            for (int i = 0; i < 4; i++) {
                const int row = wave * 32 + i * 8 + (lane >> 3);
                const int lb  = (lane & 7) ^ (row & 7);
                const bf16* g = xb + (size_t)(bm + row) * 1024 + k0 + lb * 8;
                dma16((const void*)g, (void*)&As1[wave * 32 + i * 8][0]);
            }
        } else {
#pragma unroll
            for (int it = 0; it < 2; it++) {
                const int r  = (tid >> 2) + it * 64;
                const int cq = (tid & 3) * 16;
                const float* src = x + (size_t)(bm + r) * 1024 + k0 + cq;
                float4 f0 = *(const float4*)src,       f1 = *(const float4*)(src + 4);
                float4 f2 = *(const float4*)(src + 8), f3 = *(const float4*)(src + 12);
                bf16x8 v0, v1;
                v0[0]=(bf16)f0.x; v0[1]=(bf16)f0.y; v0[2]=(bf16)f0.z; v0[3]=(bf16)f0.w;
                v0[4]=(bf16)f1.x; v0[5]=(bf16)f1.y; v0[6]=(bf16)f1.z; v0[7]=(bf16)f1.w;
                v1[0]=(bf16)f2.x; v1[1]=(bf16)f2.y; v1[2]=(bf16)f2.z; v1[3]=(bf16)f2.w;
                v1[4]=(bf16)f3.x; v1[5]=(bf16)f3.y; v1[6]=(bf16)f3.z; v1[7]=(bf16)f3.w;
                *(bf16x8*)&As0[r][cq]     = v0;
                *(bf16x8*)&As0[r][cq + 8] = v1;
            }
        }
        __syncthreads();

#pragma unroll
        for (int kk = 0; kk < 2; kk++) {
            bf16x8 a[4], b[4];
#pragma unroll
            for (int tm = 0; tm < 4; tm++) {
                const int m = wm + tm * 16 + l16;
                if (AMODE) {
                    const int phys = (kk * 4 + quad) ^ (m & 7);
                    a[tm] = *(const bf16x8*)&As1[m][phys * 8];
                } else {
                    a[tm] = *(const bf16x8*)&As0[m][kk * 32 + quad * 8];
                }
            }
#pragma unroll
            for (int tn = 0; tn < 4; tn++) {
                const int n = wn + tn * 16 + l16;
                const int phys = (kk * 4 + quad) ^ (n & 7);
                b[tn] = *(const bf16x8*)&Bs[n][phys * 8];
            }
#pragma unroll
            for (int tm = 0; tm < 4; tm++)
#pragma unroll
                for (int tn = 0; tn < 4; tn++)
                    acc[tm][tn] = __builtin_amdgcn_mfma_f32_16x16x32_bf16(a[tm], b[tn], acc[tm][tn], 0, 0, 0);
        }
    }

    if (zz < 2) {
        bf16* dst = (zz == 0) ? Qb : Kb;
        // K pre-scaled by 1/sqrt(64) * log2(e): softmax in exp2 domain
        const float sc = (zz == 1) ? 0.18033688f : 1.0f;
#pragma unroll
        for (int tm = 0; tm < 4; tm++)
#pragma unroll
            for (int tn = 0; tn < 4; tn++)
#pragma unroll
                for (int r = 0; r < 4; r++) {
                    const int m = bm + wm + tm * 16 + quad * 4 + r;
                    const int n = bn + wn + tn * 16 + l16;
                    const int bb = m >> 11, s = m & 2047;
                    const int h = n >> 6, d = n & 63;
                    dst[(((size_t)(bb * Hh + h)) * Sq + s) * HDim + d] = (bf16)(acc[tm][tn][r] * sc);
                }
    } else {
        __syncthreads();
        bf16 (*CT)[136] = (bf16(*)[136])smem;
#pragma unroll
        for (int tm = 0; tm < 4; tm++)
#pragma unroll
            for (int tn = 0; tn < 4; tn++)
#pragma unroll
                for (int r = 0; r < 4; r++) {
                    const int ml = wm + tm * 16 + quad * 4 + r;
                    const int nl = wn + tn * 16 + l16;
                    CT[nl][ml] = (bf16)acc[tm][tn][r];
                }
        __syncthreads();
        const int nl = tid >> 1, part = tid & 1;
        const int n = bn + nl, h = n >> 6, d = n & 63;
        const int bbv = bm >> 11, s0v = bm & 2047;
        bf16* o = VT + (((size_t)(bbv * Hh + h)) * HDim + d) * Sq + s0v + part * 64;
#pragma unroll
        for (int i = 0; i < 8; i++)
            *(bf16x8*)(o + i * 8) = *(const bf16x8*)&CT[nl][part * 64 + i * 8];
    }
}

// ---------------------------------------------------------------------------
// Kernel 2: flash-style causal attention, S-transposed, DOUBLE-BUFFERED DMA.
// grid = (8, nbh).  128-row q-tiles {x, 15-x}, 32 q-rows/wave.
// K/V tile kt+1 prefetched via global_load_lds while computing tile kt.
// ---------------------------------------------------------------------------
__global__ __launch_bounds__(256)
void attn(const bf16* __restrict__ Qb, const bf16* __restrict__ Kb,
          const bf16* __restrict__ VTg, bf16* __restrict__ Cx)
{
    const int bh = blockIdx.y;
    const int bl = bh >> 4, h = bh & 15;

    __shared__ __align__(16) bf16 Kl[2][64][64];   // [buf][key][d], 16B-swizzled
    __shared__ __align__(16) bf16 Vt[2][64][64];   // [buf][d][key], 16B-swizzled
    __shared__ __align__(16) bf16 PlT[4][32][72];  // per-wave P^T: [qrow][key]

    const int tid  = threadIdx.x;
    const int wave = tid >> 6, lane = tid & 63, quad = lane >> 4, l16 = lane & 15;

    const int drow = wave * 16 + (lane >> 3);      // DMA row within tile half
    const int dlb  = (lane & 7) ^ (drow & 7);      // swizzled 16B block
    // NOTE: BOTH bases carry the per-lane swizzle offset dlb*8 (R5 bug: V lacked it)
    const bf16* Kbase = Kb  + ((size_t)bh * Sq + drow) * HDim + dlb * 8;
    const bf16* Vbase = VTg + ((size_t)bh * HDim + drow) * Sq + dlb * 8;

    for (int pass = 0; pass < 2; pass++) {
        const int qt = (pass == 0) ? (int)blockIdx.x : 15 - (int)blockIdx.x;
        const int q0 = qt * 128 + wave * 32;

        bf16x8 bq[2][2];
#pragma unroll
        for (int nt = 0; nt < 2; nt++) {
            const bf16* Qrow = Qb + ((size_t)bh * Sq + q0 + nt * 16 + l16) * HDim;
            bq[nt][0] = *(const bf16x8*)(Qrow + quad * 8);
            bq[nt][1] = *(const bf16x8*)(Qrow + 32 + quad * 8);
        }

        floatx4 acc[4][2];
#pragma unroll
        for (int i = 0; i < 4; i++)
#pragma unroll
            for (int j = 0; j < 2; j++) acc[i][j] = (floatx4){0.f, 0.f, 0.f, 0.f};
        float m_old[2] = {-1e30f, -1e30f}, l_sum[2] = {0.f, 0.f};

        const int nk = 2 * qt + 2;

        // protect buf0 from previous pass's readers, then prefetch tile 0
        __syncthreads();
#pragma unroll
        for (int i = 0; i < 2; i++) {
            dma16((const void*)(Kbase + (size_t)(i * 8) * HDim),
                  (void*)&Kl[0][wave * 16 + i * 8][0]);
            dma16((const void*)(Vbase + i * 8 * Sq),
                  (void*)&Vt[0][wave * 16 + i * 8][0]);
        }

        for (int kt = 0; kt < nk; kt++) {
            const int cur = kt & 1, nxt = cur ^ 1;
            __syncthreads();   // drains my DMA (vmcnt) + all waves done with nxt buf
            if (kt + 1 < nk) {
#pragma unroll
                for (int i = 0; i < 2; i++) {
                    dma16((const void*)(Kbase + (size_t)((kt + 1) * 64 + i * 8) * HDim),
                          (void*)&Kl[nxt][wave * 16 + i * 8][0]);
                    dma16((const void*)(Vbase + (kt + 1) * 64 + i * 8 * Sq),
                          (void*)&Vt[nxt][wave * 16 + i * 8][0]);
                }
            }

            // S^T[key][qrow] = K · Q^T   (K pre-scaled to log2 domain)
            floatx4 sT[4][2];
#pragma unroll
            for (int mt = 0; mt < 4; mt++) {
                const int kr = mt * 16 + l16;
                bf16x8 ak0 = *(const bf16x8*)&Kl[cur][kr][(quad ^ (kr & 7)) * 8];
                bf16x8 ak1 = *(const bf16x8*)&Kl[cur][kr][((4 + quad) ^ (kr & 7)) * 8];
#pragma unroll
                for (int nt = 0; nt < 2; nt++) {
                    floatx4 z = (floatx4){0.f, 0.f, 0.f, 0.f};
                    z = __builtin_amdgcn_mfma_f32_16x16x32_bf16(ak0, bq[nt][0], z, 0, 0, 0);
                    z = __builtin_amdgcn_mfma_f32_16x16x32_bf16(ak1, bq[nt][1], z, 0, 0, 0);
                    sT[mt][nt] = z;
                }
            }

            if (kt >= nk - 2) {
#pragma unroll
                for (int mt = 0; mt < 4; mt++)
#pragma unroll
                    for (int nt = 0; nt < 2; nt++)
#pragma unroll
                        for (int r = 0; r < 4; r++) {
                            const int key  = kt * 64 + mt * 16 + quad * 4 + r;
                            const int qrow = q0 + nt * 16 + l16;
                            if (key > qrow) sT[mt][nt][r] = -1e30f;
                        }
            }

            // online softmax in exp2 domain
            float alpha[2];
#pragma unroll
            for (int nt = 0; nt < 2; nt++) {
                float mx = -1e30f;
#pragma unroll
                for (int mt = 0; mt < 4; mt++) {
                    float a01 = fmaxf(sT[mt][nt][0], sT[mt][nt][1]);
                    float a23 = fmaxf(sT[mt][nt][2], sT[mt][nt][3]);
                    mx = fmaxf(mx, fmaxf(a01, a23));
                }
                mx = fmaxf(mx, __shfl_xor(mx, 16, 64));
                mx = fmaxf(mx, __shfl_xor(mx, 32, 64));
                const float mn = fmaxf(m_old[nt], mx);
                alpha[nt] = exp2f(m_old[nt] - mn);
                m_old[nt] = mn;
                float rs = 0.f;
#pragma unroll
                for (int mt = 0; mt < 4; mt++)
#pragma unroll
                    for (int r = 0; r < 4; r++) {
                        const float e = exp2f(sT[mt][nt][r] - mn);
                        sT[mt][nt][r] = e;
                        rs += e;
                    }
                rs += __shfl_xor(rs, 16, 64);
                rs += __shfl_xor(rs, 32, 64);
                l_sum[nt] = l_sum[nt] * alpha[nt] + rs;
            }

            // P^T -> per-wave LDS (packed b64), rescale O accumulator
#pragma unroll
            for (int mt = 0; mt < 4; mt++)
#pragma unroll
                for (int nt = 0; nt < 2; nt++) {
                    uint2 pk;
                    pk.x = pk_bf16(sT[mt][nt][0], sT[mt][nt][1]);
                    pk.y = pk_bf16(sT[mt][nt][2], sT[mt][nt][3]);
                    *(uint2*)&PlT[wave][nt * 16 + l16][mt * 16 + quad * 4] = pk;
                    acc[mt][nt] *= alpha[nt];
                }
            // no barrier: PlT[wave] is wave-private

            // O^T += V^T · P^T
#pragma unroll
            for (int ks = 0; ks < 2; ks++) {
                bf16x8 bp[2];
#pragma unroll
                for (int nt = 0; nt < 2; nt++)
                    bp[nt] = *(const bf16x8*)&PlT[wave][nt * 16 + l16][ks * 32 + quad * 8];
#pragma unroll
                for (int mt = 0; mt < 4; mt++) {
                    const int vr = mt * 16 + l16;
                    bf16x8 av = *(const bf16x8*)&Vt[cur][vr][((ks * 4 + quad) ^ (vr & 7)) * 8];
#pragma unroll
                    for (int nt = 0; nt < 2; nt++)
                        acc[mt][nt] = __builtin_amdgcn_mfma_f32_16x16x32_bf16(av, bp[nt], acc[mt][nt], 0, 0, 0);
                }
            }
        }

        // epilogue
#pragma unroll
        for (int nt = 0; nt < 2; nt++) {
            const float inv = __builtin_amdgcn_rcpf(l_sum[nt]);
            const int qrow = q0 + nt * 16 + l16;
#pragma unroll
            for (int mt = 0; mt < 4; mt++) {
                uint2 pk;
                pk.x = pk_bf16(acc[mt][nt][0] * inv, acc[mt][nt][1] * inv);
                pk.y = pk_bf16(acc[mt][nt][2] * inv, acc[mt][nt][3] * inv);
                *(uint2*)(Cx + ((size_t)(bl * Sq + qrow)) * Dm + h * HDim + mt * 16 + quad * 4) = pk;
            }
        }
    }
}

// ---------------------------------------------------------------------------
// Kernel 3: output projection.  Cx bf16 @ WoT + bo -> fp32 out.
// ---------------------------------------------------------------------------
__global__ __launch_bounds__(256, 2)
void out_gemm(const bf16* __restrict__ Cx, const bf16* __restrict__ WtO,
              const float* __restrict__ bo, float* __restrict__ out, int mbase)
{
    __shared__ __align__(16) bf16 As2[128][64];
    __shared__ __align__(16) bf16 Bs2[128][64];

    const int tid  = threadIdx.x;
    const int wave = tid >> 6, lane = tid & 63, quad = lane >> 4, l16 = lane & 15;
    const int bm = blockIdx.y * 128, bn = blockIdx.x * 128;
    const int wm = (wave >> 1) * 64, wn = (wave & 1) * 64;

    floatx4 acc[4][4];
#pragma unroll
    for (int i = 0; i < 4; i++)
#pragma unroll
        for (int j = 0; j < 4; j++) acc[i][j] = (floatx4){0.f, 0.f, 0.f, 0.f};

    for (int k0 = 0; k0 < 1024; k0 += 64) {
        __syncthreads();
#pragma unroll
        for (int i = 0; i < 4; i++) {
            const int row = wave * 32 + i * 8 + (lane >> 3);
            const int lb  = (lane & 7) ^ (row & 7);
            const bf16* ga = Cx  + (size_t)(bm + row) * 1024 + k0 + lb * 8;
            const bf16* gb = WtO + (size_t)(bn + row) * 1024 + k0 + lb * 8;
            dma16((const void*)ga, (void*)&As2[wave * 32 + i * 8][0]);
            dma16((const void*)gb, (void*)&Bs2[wave * 32 + i * 8][0]);
        }
        __syncthreads();

#pragma unroll
        for (int kk = 0; kk < 2; kk++) {
            bf16x8 a[4], b[4];
#pragma unroll
            for (int tm = 0; tm < 4; tm++) {
                const int m = wm + tm * 16 + l16;
                const int phys = (kk * 4 + quad) ^ (m & 7);
                a[tm] = *(const bf16x8*)&As2[m][phys * 8];
            }
#pragma unroll
            for (int tn = 0; tn < 4; tn++) {
                const int n = wn + tn * 16 + l16;
                const int phys = (kk * 4 + quad) ^ (n & 7);
                b[tn] = *(const bf16x8*)&Bs2[n][phys * 8];
            }
#pragma unroll
            for (int tm = 0; tm < 4; tm++)
#pragma unroll
                for (int tn = 0; tn < 4; tn++)
                    acc[tm][tn] = __builtin_amdgcn_mfma_f32_16x16x32_bf16(a[tm], b[tn], acc[tm][tn], 0, 0, 0);
        }
    }

#pragma unroll
    for (int tm = 0; tm < 4; tm++)
#pragma unroll
        for (int tn = 0; tn < 4; tn++)
#pragma unroll
            for (int r = 0; r < 4; r++) {
                const int m = bm + wm + tm * 16 + quad * 4 + r;
                const int n = bn + wn + tn * 16 + l16;
                out[(size_t)(mbase + m) * 1024 + n] = acc[tm][tn][r] + bo[n];
            }
}

// ---------------------------------------------------------------------------
extern "C" void kernel_launch(void* const* d_in, const int* in_sizes, int n_in,
                              void* d_out, int out_size, void* d_ws, size_t ws_size,
                              hipStream_t stream)
{
    const float* x  = (const float*)d_in[0];
    const float* Wq = (const float*)d_in[1];
    const float* Wk = (const float*)d_in[2];
    const float* Wv = (const float*)d_in[3];
    const float* Wo = (const float*)d_in[4];
    const float* bo = (const float*)d_in[5];
    float* out = (float*)d_out;

    const size_t M1 = 1024 * 1024;
    const size_t XE = (size_t)8192 * 1024;

    if (ws_size >= (size_t)72 * 1024 * 1024) {
        // primary: Wt 8MB | xb 16 (aliased by Cx) | Qb 16 | Kb 16 | VT 16
        bf16* Wt = (bf16*)d_ws;
        bf16* xb = Wt + 4 * M1;
        bf16* Qb = xb + XE;
        bf16* Kb = Qb + XE;
        bf16* VT = Kb + XE;
        bf16* Cx = xb;  // alias: xb dead after qkv_gemm

        conv_x<<<dim3(4096), 256, 0, stream>>>(x, xb);
        prep_weights<<<dim3(16, 16, 4), 256, 0, stream>>>(Wq, Wk, Wv, Wo, Wt);
        qkv_gemm<1><<<dim3(8, 64, 3), 256, 0, stream>>>(x, xb, Wt, Qb, Kb, VT);
        attn<<<dim3(8, 64), 256, 0, stream>>>(Qb, Kb, VT, Cx);
        out_gemm<<<dim3(8, 64), 256, 0, stream>>>(Cx, Wt + 3 * M1, bo, out, 0);
    } else {
        // fallback (64 MB): Wt 8 | Qb 16 | Kb 16 | VT 16 | Cx 8
        bf16* Wt = (bf16*)d_ws;
        bf16* Qb = Wt + 4 * M1;
        bf16* Kb = Qb + XE;
        bf16* VT = Kb + XE;
        bf16* Cx = VT + XE;

        prep_weights<<<dim3(16, 16, 4), 256, 0, stream>>>(Wq, Wk, Wv, Wo, Wt);
        qkv_gemm<0><<<dim3(8, 64, 3), 256, 0, stream>>>(x, nullptr, Wt, Qb, Kb, VT);
        const size_t chunk = (size_t)2 * Hh * Sq * HDim;
        for (int c = 0; c < 2; c++) {
            attn<<<dim3(8, 32), 256, 0, stream>>>(Qb + c * chunk, Kb + c * chunk,
                                                  VT + c * chunk, Cx);
            out_gemm<<<dim3(8, 32), 256, 0, stream>>>(Cx, Wt + 3 * M1, bo, out, c * 4096);
        }
    }
}

// Round 7
// 288.685 us; speedup vs baseline: 1.0563x; 1.0563x over previous
//
#include <hip/hip_runtime.h>
#include <math.h>
#include <stdint.h>

typedef __bf16 bf16;
typedef bf16 bf16x8 __attribute__((ext_vector_type(8)));
typedef float floatx4 __attribute__((ext_vector_type(4)));

static constexpr int Sq = 2048, Dm = 1024, Hh = 16, HDim = 64;

#define GAS __attribute__((address_space(1)))
#define LAS __attribute__((address_space(3)))

// async global->LDS DMA, 16 B per lane; lds base wave-uniform, lane i -> base + i*16
__device__ __forceinline__ void dma16(const void* g, void* l) {
    __builtin_amdgcn_global_load_lds((const GAS void*)g, (LAS void*)l, 16, 0, 0);
}

__device__ __forceinline__ uint32_t pk_bf16(float a, float b) {
    unsigned short lo = __builtin_bit_cast(unsigned short, (bf16)a);
    unsigned short hi = __builtin_bit_cast(unsigned short, (bf16)b);
    return (uint32_t)lo | ((uint32_t)hi << 16);
}

// ---------------------------------------------------------------------------
// Kernel A: x fp32 -> bf16 (one pass).  8 elems/thread.
// ---------------------------------------------------------------------------
__global__ __launch_bounds__(256)
void conv_x(const float* __restrict__ x, bf16* __restrict__ xb)
{
    const size_t i = ((size_t)blockIdx.x * 256 + threadIdx.x) * 8;
    float4 f0 = *(const float4*)(x + i);
    float4 f1 = *(const float4*)(x + i + 4);
    bf16x8 v;
    v[0]=(bf16)f0.x; v[1]=(bf16)f0.y; v[2]=(bf16)f0.z; v[3]=(bf16)f0.w;
    v[4]=(bf16)f1.x; v[5]=(bf16)f1.y; v[6]=(bf16)f1.z; v[7]=(bf16)f1.w;
    *(bf16x8*)(xb + i) = v;
}

// ---------------------------------------------------------------------------
// Kernel 0: weight prep.  W fp32 [k][n] -> Wt bf16 [n][k], 4 matrices.
// ---------------------------------------------------------------------------
__global__ __launch_bounds__(256)
void prep_weights(const float* __restrict__ Wq, const float* __restrict__ Wk,
                  const float* __restrict__ Wv, const float* __restrict__ Wo,
                  bf16* __restrict__ Wt)
{
    const int w = blockIdx.z;
    const float* W = (w == 0) ? Wq : (w == 1) ? Wk : (w == 2) ? Wv : Wo;
    bf16* dst = Wt + (size_t)w * 1024 * 1024;
    const int k0 = blockIdx.x * 64, n0 = blockIdx.y * 64;
    __shared__ uint32_t Tl[64][33];
    const int t = threadIdx.x;
    {
        const int c8 = (t & 7) * 8;
        const int kp = t >> 3;
        const float* r0 = W + (size_t)(k0 + 2 * kp) * 1024 + n0 + c8;
        const float* r1 = r0 + 1024;
        float4 a0 = *(const float4*)r0, a1 = *(const float4*)(r0 + 4);
        float4 b0 = *(const float4*)r1, b1 = *(const float4*)(r1 + 4);
        float ra[8] = {a0.x, a0.y, a0.z, a0.w, a1.x, a1.y, a1.z, a1.w};
        float rb[8] = {b0.x, b0.y, b0.z, b0.w, b1.x, b1.y, b1.z, b1.w};
#pragma unroll
        for (int j = 0; j < 8; j++)
            Tl[c8 + j][kp] = pk_bf16(ra[j], rb[j]);
    }
    __syncthreads();
    {
        const int c = t >> 2, dq = (t & 3) * 8;
        uint32_t d[8];
#pragma unroll
        for (int i = 0; i < 8; i++) d[i] = Tl[c][dq + i];
        uint32_t* o = (uint32_t*)(dst + (size_t)(n0 + c) * 1024 + k0 + dq * 2);
        *(uint4*)o       = make_uint4(d[0], d[1], d[2], d[3]);
        *(uint4*)(o + 4) = make_uint4(d[4], d[5], d[6], d[7]);
    }
}

// ---------------------------------------------------------------------------
// Kernel 1: QKV projection.  AMODE=1: bf16 xb via DMA (primary);
// AMODE=0: fp32 x (fallback).  128x128 tile, BK=64.
// grid (64 Mtiles, 8 Ntiles, 3): XCD = Mtile%8 -> A-tile reuse in XCD L2.
// K output pre-scaled by 0.125*log2(e) (softmax runs in exp2 domain).
// ---------------------------------------------------------------------------
template <int AMODE>
__global__ __launch_bounds__(256, 2)
void qkv_gemm(const float* __restrict__ x, const bf16* __restrict__ xb,
              const bf16* __restrict__ Wt,
              bf16* __restrict__ Qb, bf16* __restrict__ Kb, bf16* __restrict__ VT)
{
    const int zz = blockIdx.z;
    const bf16* Wsel = Wt + (size_t)zz * 1024 * 1024;

    __shared__ __align__(16) unsigned char smem[34816];
    bf16 (*As1)[64] = (bf16(*)[64])smem;
    bf16 (*As0)[72] = (bf16(*)[72])smem;
    bf16 (*Bs)[64]  = (bf16(*)[64])(smem + (AMODE ? 16384 : 18432));

    const int tid  = threadIdx.x;
    const int wave = tid >> 6, lane = tid & 63, quad = lane >> 4, l16 = lane & 15;
    const int bm = blockIdx.x * 128, bn = blockIdx.y * 128;   // XCD = blockIdx.x % 8
    const int wm = (wave >> 1) * 64, wn = (wave & 1) * 64;

    floatx4 acc[4][4];
#pragma unroll
    for (int i = 0; i < 4; i++)
#pragma unroll
        for (int j = 0; j < 4; j++) acc[i][j] = (floatx4){0.f, 0.f, 0.f, 0.f};

    for (int k0 = 0; k0 < 1024; k0 += 64) {
        __syncthreads();
#pragma unroll
        for (int i = 0; i < 4; i++) {
            const int row = wave * 32 + i * 8 + (lane >> 3);
            const int lb  = (lane & 7) ^ (row & 7);
            const bf16* g = Wsel + (size_t)(bn + row) * 1024 + k0 + lb * 8;
            dma16((const void*)g, (void*)&Bs[wave * 32 + i * 8][0]);
        }
        if (AMODE) {
#pragma unroll
            for (int i = 0; i < 4; i++) {
                const int row = wave * 32 + i * 8 + (lane >> 3);
                const int lb  = (lane & 7) ^ (row & 7);
                const bf16* g = xb + (size_t)(bm + row) * 1024 + k0 + lb * 8;
                dma16((const void*)g, (void*)&As1[wave * 32 + i * 8][0]);
            }
        } else {
#pragma unroll
            for (int it = 0; it < 2; it++) {
                const int r  = (tid >> 2) + it * 64;
                const int cq = (tid & 3) * 16;
                const float* src = x + (size_t)(bm + r) * 1024 + k0 + cq;
                float4 f0 = *(const float4*)src,       f1 = *(const float4*)(src + 4);
                float4 f2 = *(const float4*)(src + 8), f3 = *(const float4*)(src + 12);
                bf16x8 v0, v1;
                v0[0]=(bf16)f0.x; v0[1]=(bf16)f0.y; v0[2]=(bf16)f0.z; v0[3]=(bf16)f0.w;
                v0[4]=(bf16)f1.x; v0[5]=(bf16)f1.y; v0[6]=(bf16)f1.z; v0[7]=(bf16)f1.w;
                v1[0]=(bf16)f2.x; v1[1]=(bf16)f2.y; v1[2]=(bf16)f2.z; v1[3]=(bf16)f2.w;
                v1[4]=(bf16)f3.x; v1[5]=(bf16)f3.y; v1[6]=(bf16)f3.z; v1[7]=(bf16)f3.w;
                *(bf16x8*)&As0[r][cq]     = v0;
                *(bf16x8*)&As0[r][cq + 8] = v1;
            }
        }
        __syncthreads();

#pragma unroll
        for (int kk = 0; kk < 2; kk++) {
            bf16x8 a[4], b[4];
#pragma unroll
            for (int tm = 0; tm < 4; tm++) {
                const int m = wm + tm * 16 + l16;
                if (AMODE) {
                    const int phys = (kk * 4 + quad) ^ (m & 7);
                    a[tm] = *(const bf16x8*)&As1[m][phys * 8];
                } else {
                    a[tm] = *(const bf16x8*)&As0[m][kk * 32 + quad * 8];
                }
            }
#pragma unroll
            for (int tn = 0; tn < 4; tn++) {
                const int n = wn + tn * 16 + l16;
                const int phys = (kk * 4 + quad) ^ (n & 7);
                b[tn] = *(const bf16x8*)&Bs[n][phys * 8];
            }
#pragma unroll
            for (int tm = 0; tm < 4; tm++)
#pragma unroll
                for (int tn = 0; tn < 4; tn++)
                    acc[tm][tn] = __builtin_amdgcn_mfma_f32_16x16x32_bf16(a[tm], b[tn], acc[tm][tn], 0, 0, 0);
        }
    }

    if (zz < 2) {
        bf16* dst = (zz == 0) ? Qb : Kb;
        // K pre-scaled by 1/sqrt(64) * log2(e): softmax in exp2 domain
        const float sc = (zz == 1) ? 0.18033688f : 1.0f;
#pragma unroll
        for (int tm = 0; tm < 4; tm++)
#pragma unroll
            for (int tn = 0; tn < 4; tn++)
#pragma unroll
                for (int r = 0; r < 4; r++) {
                    const int m = bm + wm + tm * 16 + quad * 4 + r;
                    const int n = bn + wn + tn * 16 + l16;
                    const int bb = m >> 11, s = m & 2047;
                    const int h = n >> 6, d = n & 63;
                    dst[(((size_t)(bb * Hh + h)) * Sq + s) * HDim + d] = (bf16)(acc[tm][tn][r] * sc);
                }
    } else {
        __syncthreads();
        bf16 (*CT)[136] = (bf16(*)[136])smem;
#pragma unroll
        for (int tm = 0; tm < 4; tm++)
#pragma unroll
            for (int tn = 0; tn < 4; tn++)
#pragma unroll
                for (int r = 0; r < 4; r++) {
                    const int ml = wm + tm * 16 + quad * 4 + r;
                    const int nl = wn + tn * 16 + l16;
                    CT[nl][ml] = (bf16)acc[tm][tn][r];
                }
        __syncthreads();
        const int nl = tid >> 1, part = tid & 1;
        const int n = bn + nl, h = n >> 6, d = n & 63;
        const int bbv = bm >> 11, s0v = bm & 2047;
        bf16* o = VT + (((size_t)(bbv * Hh + h)) * HDim + d) * Sq + s0v + part * 64;
#pragma unroll
        for (int i = 0; i < 8; i++)
            *(bf16x8*)(o + i * 8) = *(const bf16x8*)&CT[nl][part * 64 + i * 8];
    }
}

// ---------------------------------------------------------------------------
// Kernel 2: flash-style causal attention, S-transposed, REGISTER-STAGED
// software pipeline (global_load -> VGPR survives barriers; ds_write after
// the barrier, one compute-phase after issue).
// grid = (nbh, 8): XCD = bh % 8 -> all q-tiles of a head share one L2.
// 128-row q-tiles {y, 15-y}, 32 q-rows/wave.
// ---------------------------------------------------------------------------
__global__ __launch_bounds__(256)
void attn(const bf16* __restrict__ Qb, const bf16* __restrict__ Kb,
          const bf16* __restrict__ VTg, bf16* __restrict__ Cx)
{
    const int bh = blockIdx.x;            // XCD = bh % 8
    const int bl = bh >> 4, h = bh & 15;

    __shared__ __align__(16) bf16 Kl[64][64];      // [key][d], 16B-swizzled
    __shared__ __align__(16) bf16 Vt[64][64];      // [d][key], 16B-swizzled
    __shared__ __align__(16) bf16 PlT[4][32][72];  // per-wave P^T

    const int tid  = threadIdx.x;
    const int wave = tid >> 6, lane = tid & 63, quad = lane >> 4, l16 = lane & 15;

    // staging geometry: wave w stages rows 16w..16w+15, lane -> (row, chunk)
    const int srow = wave * 16 + (lane >> 3);            // rows srow, srow+8
    const int sc   = lane & 7;                           // logical 16B chunk
    const int sp   = (sc ^ (lane >> 3)) * 8;             // phys offset (same both rows)
    const bf16* Kg = Kb  + ((size_t)bh * Sq + srow) * HDim + sc * 8;
    const bf16* Vg = VTg + ((size_t)bh * HDim + srow) * Sq + sc * 8;

    uint4 kreg[2], vreg[2];
    auto loadt = [&](int kt) {
        kreg[0] = *(const uint4*)(Kg + (size_t)(kt * 64) * HDim);
        kreg[1] = *(const uint4*)(Kg + (size_t)(kt * 64 + 8) * HDim);
        vreg[0] = *(const uint4*)(Vg + kt * 64);
        vreg[1] = *(const uint4*)(Vg + kt * 64 + 8 * Sq);
    };

    for (int pass = 0; pass < 2; pass++) {
        const int qt = (pass == 0) ? (int)blockIdx.y : 15 - (int)blockIdx.y;
        const int q0 = qt * 128 + wave * 32;

        bf16x8 bq[2][2];
#pragma unroll
        for (int nt = 0; nt < 2; nt++) {
            const bf16* Qrow = Qb + ((size_t)bh * Sq + q0 + nt * 16 + l16) * HDim;
            bq[nt][0] = *(const bf16x8*)(Qrow + quad * 8);
            bq[nt][1] = *(const bf16x8*)(Qrow + 32 + quad * 8);
        }

        floatx4 acc[4][2];
#pragma unroll
        for (int i = 0; i < 4; i++)
#pragma unroll
            for (int j = 0; j < 2; j++) acc[i][j] = (floatx4){0.f, 0.f, 0.f, 0.f};
        float m_old[2] = {-1e30f, -1e30f}, l_sum[2] = {0.f, 0.f};

        const int nk = 2 * qt + 2;
        loadt(0);

        for (int kt = 0; kt < nk; kt++) {
            __syncthreads();   // all waves done reading previous tile (LDS only)
            // commit regs -> LDS (compiler waits vmcnt for kreg/vreg here,
            // i.e. a full compute-phase after they were issued)
            *(uint4*)&Kl[srow][sp]     = kreg[0];
            *(uint4*)&Kl[srow + 8][sp] = kreg[1];
            *(uint4*)&Vt[srow][sp]     = vreg[0];
            *(uint4*)&Vt[srow + 8][sp] = vreg[1];
            __syncthreads();   // LDS writes visible (lgkm drain only)
            if (kt + 1 < nk) loadt(kt + 1);   // prefetch: VGPR loads survive barriers

            // S^T[key][qrow] = K · Q^T   (K pre-scaled to log2 domain)
            floatx4 sT[4][2];
#pragma unroll
            for (int mt = 0; mt < 4; mt++) {
                const int kr = mt * 16 + l16;
                bf16x8 ak0 = *(const bf16x8*)&Kl[kr][(quad ^ (kr & 7)) * 8];
                bf16x8 ak1 = *(const bf16x8*)&Kl[kr][((4 + quad) ^ (kr & 7)) * 8];
#pragma unroll
                for (int nt = 0; nt < 2; nt++) {
                    floatx4 z = (floatx4){0.f, 0.f, 0.f, 0.f};
                    z = __builtin_amdgcn_mfma_f32_16x16x32_bf16(ak0, bq[nt][0], z, 0, 0, 0);
                    z = __builtin_amdgcn_mfma_f32_16x16x32_bf16(ak1, bq[nt][1], z, 0, 0, 0);
                    sT[mt][nt] = z;
                }
            }

            if (kt >= nk - 2) {
#pragma unroll
                for (int mt = 0; mt < 4; mt++)
#pragma unroll
                    for (int nt = 0; nt < 2; nt++)
#pragma unroll
                        for (int r = 0; r < 4; r++) {
                            const int key  = kt * 64 + mt * 16 + quad * 4 + r;
                            const int qrow = q0 + nt * 16 + l16;
                            if (key > qrow) sT[mt][nt][r] = -1e30f;
                        }
            }

            // online softmax in exp2 domain
            float alpha[2];
#pragma unroll
            for (int nt = 0; nt < 2; nt++) {
                float mx = -1e30f;
#pragma unroll
                for (int mt = 0; mt < 4; mt++) {
                    float a01 = fmaxf(sT[mt][nt][0], sT[mt][nt][1]);
                    float a23 = fmaxf(sT[mt][nt][2], sT[mt][nt][3]);
                    mx = fmaxf(mx, fmaxf(a01, a23));
                }
                mx = fmaxf(mx, __shfl_xor(mx, 16, 64));
                mx = fmaxf(mx, __shfl_xor(mx, 32, 64));
                const float mn = fmaxf(m_old[nt], mx);
                alpha[nt] = exp2f(m_old[nt] - mn);
                m_old[nt] = mn;
                float rs = 0.f;
#pragma unroll
                for (int mt = 0; mt < 4; mt++)
#pragma unroll
                    for (int r = 0; r < 4; r++) {
                        const float e = exp2f(sT[mt][nt][r] - mn);
                        sT[mt][nt][r] = e;
                        rs += e;
                    }
                rs += __shfl_xor(rs, 16, 64);
                rs += __shfl_xor(rs, 32, 64);
                l_sum[nt] = l_sum[nt] * alpha[nt] + rs;
            }

            // P^T -> per-wave LDS (packed b64), rescale O accumulator
#pragma unroll
            for (int mt = 0; mt < 4; mt++)
#pragma unroll
                for (int nt = 0; nt < 2; nt++) {
                    uint2 pk;
                    pk.x = pk_bf16(sT[mt][nt][0], sT[mt][nt][1]);
                    pk.y = pk_bf16(sT[mt][nt][2], sT[mt][nt][3]);
                    *(uint2*)&PlT[wave][nt * 16 + l16][mt * 16 + quad * 4] = pk;
                    acc[mt][nt] *= alpha[nt];
                }
            // no barrier: PlT[wave] is wave-private

            // O^T += V^T · P^T
#pragma unroll
            for (int ks = 0; ks < 2; ks++) {
                bf16x8 bp[2];
#pragma unroll
                for (int nt = 0; nt < 2; nt++)
                    bp[nt] = *(const bf16x8*)&PlT[wave][nt * 16 + l16][ks * 32 + quad * 8];
#pragma unroll
                for (int mt = 0; mt < 4; mt++) {
                    const int vr = mt * 16 + l16;
                    bf16x8 av = *(const bf16x8*)&Vt[vr][((ks * 4 + quad) ^ (vr & 7)) * 8];
#pragma unroll
                    for (int nt = 0; nt < 2; nt++)
                        acc[mt][nt] = __builtin_amdgcn_mfma_f32_16x16x32_bf16(av, bp[nt], acc[mt][nt], 0, 0, 0);
                }
            }
        }

        // epilogue
#pragma unroll
        for (int nt = 0; nt < 2; nt++) {
            const float inv = __builtin_amdgcn_rcpf(l_sum[nt]);
            const int qrow = q0 + nt * 16 + l16;
#pragma unroll
            for (int mt = 0; mt < 4; mt++) {
                uint2 pk;
                pk.x = pk_bf16(acc[mt][nt][0] * inv, acc[mt][nt][1] * inv);
                pk.y = pk_bf16(acc[mt][nt][2] * inv, acc[mt][nt][3] * inv);
                *(uint2*)(Cx + ((size_t)(bl * Sq + qrow)) * Dm + h * HDim + mt * 16 + quad * 4) = pk;
            }
        }
    }
}

// ---------------------------------------------------------------------------
// Kernel 3: output projection.  Cx bf16 @ WoT + bo -> fp32 out.
// grid (Mtiles, 8): XCD = Mtile%8 for A-tile L2 reuse.
// ---------------------------------------------------------------------------
__global__ __launch_bounds__(256, 2)
void out_gemm(const bf16* __restrict__ Cx, const bf16* __restrict__ WtO,
              const float* __restrict__ bo, float* __restrict__ out, int mbase)
{
    __shared__ __align__(16) bf16 As2[128][64];
    __shared__ __align__(16) bf16 Bs2[128][64];

    const int tid  = threadIdx.x;
    const int wave = tid >> 6, lane = tid & 63, quad = lane >> 4, l16 = lane & 15;
    const int bm = blockIdx.x * 128, bn = blockIdx.y * 128;
    const int wm = (wave >> 1) * 64, wn = (wave & 1) * 64;

    floatx4 acc[4][4];
#pragma unroll
    for (int i = 0; i < 4; i++)
#pragma unroll
        for (int j = 0; j < 4; j++) acc[i][j] = (floatx4){0.f, 0.f, 0.f, 0.f};

    for (int k0 = 0; k0 < 1024; k0 += 64) {
        __syncthreads();
#pragma unroll
        for (int i = 0; i < 4; i++) {
            const int row = wave * 32 + i * 8 + (lane >> 3);
            const int lb  = (lane & 7) ^ (row & 7);
            const bf16* ga = Cx  + (size_t)(bm + row) * 1024 + k0 + lb * 8;
            const bf16* gb = WtO + (size_t)(bn + row) * 1024 + k0 + lb * 8;
            dma16((const void*)ga, (void*)&As2[wave * 32 + i * 8][0]);
            dma16((const void*)gb, (void*)&Bs2[wave * 32 + i * 8][0]);
        }
        __syncthreads();

#pragma unroll
        for (int kk = 0; kk < 2; kk++) {
            bf16x8 a[4], b[4];
#pragma unroll
            for (int tm = 0; tm < 4; tm++) {
                const int m = wm + tm * 16 + l16;
                const int phys = (kk * 4 + quad) ^ (m & 7);
                a[tm] = *(const bf16x8*)&As2[m][phys * 8];
            }
#pragma unroll
            for (int tn = 0; tn < 4; tn++) {
                const int n = wn + tn * 16 + l16;
                const int phys = (kk * 4 + quad) ^ (n & 7);
                b[tn] = *(const bf16x8*)&Bs2[n][phys * 8];
            }
#pragma unroll
            for (int tm = 0; tm < 4; tm++)
#pragma unroll
                for (int tn = 0; tn < 4; tn++)
                    acc[tm][tn] = __builtin_amdgcn_mfma_f32_16x16x32_bf16(a[tm], b[tn], acc[tm][tn], 0, 0, 0);
        }
    }

#pragma unroll
    for (int tm = 0; tm < 4; tm++)
#pragma unroll
        for (int tn = 0; tn < 4; tn++)
#pragma unroll
            for (int r = 0; r < 4; r++) {
                const int m = bm + wm + tm * 16 + quad * 4 + r;
                const int n = bn + wn + tn * 16 + l16;
                out[(size_t)(mbase + m) * 1024 + n] = acc[tm][tn][r] + bo[n];
            }
}

// ---------------------------------------------------------------------------
extern "C" void kernel_launch(void* const* d_in, const int* in_sizes, int n_in,
                              void* d_out, int out_size, void* d_ws, size_t ws_size,
                              hipStream_t stream)
{
    const float* x  = (const float*)d_in[0];
    const float* Wq = (const float*)d_in[1];
    const float* Wk = (const float*)d_in[2];
    const float* Wv = (const float*)d_in[3];
    const float* Wo = (const float*)d_in[4];
    const float* bo = (const float*)d_in[5];
    float* out = (float*)d_out;

    const size_t M1 = 1024 * 1024;
    const size_t XE = (size_t)8192 * 1024;

    if (ws_size >= (size_t)72 * 1024 * 1024) {
        // primary: Wt 8MB | xb 16 (aliased by Cx) | Qb 16 | Kb 16 | VT 16
        bf16* Wt = (bf16*)d_ws;
        bf16* xb = Wt + 4 * M1;
        bf16* Qb = xb + XE;
        bf16* Kb = Qb + XE;
        bf16* VT = Kb + XE;
        bf16* Cx = xb;  // alias: xb dead after qkv_gemm

        conv_x<<<dim3(4096), 256, 0, stream>>>(x, xb);
        prep_weights<<<dim3(16, 16, 4), 256, 0, stream>>>(Wq, Wk, Wv, Wo, Wt);
        qkv_gemm<1><<<dim3(64, 8, 3), 256, 0, stream>>>(x, xb, Wt, Qb, Kb, VT);
        attn<<<dim3(64, 8), 256, 0, stream>>>(Qb, Kb, VT, Cx);
        out_gemm<<<dim3(64, 8), 256, 0, stream>>>(Cx, Wt + 3 * M1, bo, out, 0);
    } else {
        // fallback (64 MB): Wt 8 | Qb 16 | Kb 16 | VT 16 | Cx 8
        bf16* Wt = (bf16*)d_ws;
        bf16* Qb = Wt + 4 * M1;
        bf16* Kb = Qb + XE;
        bf16* VT = Kb + XE;
        bf16* Cx = VT + XE;

        prep_weights<<<dim3(16, 16, 4), 256, 0, stream>>>(Wq, Wk, Wv, Wo, Wt);
        qkv_gemm<0><<<dim3(64, 8, 3), 256, 0, stream>>>(x, nullptr, Wt, Qb, Kb, VT);
        const size_t chunk = (size_t)2 * Hh * Sq * HDim;
        for (int c = 0; c < 2; c++) {
            attn<<<dim3(32, 8), 256, 0, stream>>>(Qb + c * chunk, Kb + c * chunk,
                                                  VT + c * chunk, Cx);
            out_gemm<<<dim3(32, 8), 256, 0, stream>>>(Cx, Wt + 3 * M1, bo, out, c * 4096);
        }
    }
}